// Round 7
// baseline (153.279 us; speedup 1.0000x reference)
//
#include <hip/hip_runtime.h>
#include <hip/hip_bf16.h>
#include <math.h>

// Problem constants (B=2, C=128, G=16, Cg=8, K=3, H=W=192)
#define BB 2
#define CC 128
#define GG 16
#define CG 8
#define HH 192
#define WW 192
#define HM 190
#define WM 190
#define LL (HM * WM)          // 36100
#define HWSZ (HH * WW)        // 36864
#define NTRIPLE (BB * GG * 9) // 288
#define SPLIT 6               // row slices for phase1 parallelism
#define RPS 32                // rows per slice (last slice: 30)
#define STG_ROWS 34           // staged rows per channel (RPS + 2 halo)
#define STG_STRIDE (STG_ROWS * WW) // 6528 floats = 26112 B per channel

// 4-byte-aligned float4 for unaligned (dword-aligned) vector loads.
typedef float float4a __attribute__((ext_vector_type(4), aligned(4)));
typedef float float4v __attribute__((ext_vector_type(4)));

// Module-owned scratch (d_ws size unverified; writing it corrupted the
// harness pristine input copy in R0). Everything below is fully rewritten
// on every call before being read (same stream) -> identical work per call.
__device__ float g_part[NTRIPLE * SPLIT * 36]; // per-slice partial sums
__device__ int g_rel[BB * GG * 72];            // phase2: neighbor rel offset
__device__ float g_scl[BB * GG * 72];          // phase2: c_max/8

// -------- Phase 1a: LDS-staged per (b,g,j,rowslice) partial Gram sums -----
// R4-R6 showed phase1a pinned at ~43 us across scalar/float4/swizzle
// variants: global-load latency exposed in the inner loop + register churn.
// v2: stage the block's 1-2 channel row-slices into LDS once (aligned
// dwordx4, conflict-free), then the hot loop is 8 ds_read_b32 + 36 FMA per
// pixel -- no global latency, stride-4B lane access = conflict-free.
__global__ __launch_bounds__(256) void phase1a_kernel(
    const float* __restrict__ feat) {
  const int B = blockIdx.x; // 0..1727
  const int xcd = B & 7;    // XCD-locality swizzle (kept: halved FETCH)
  const int slot = B >> 3;
  const int unit = xcd * 4 + slot / 54; // (b,g) composite, 0..31
  const int r = slot % 54;
  const int j = r / 6;
  const int sl = r % 6;
  const int b = unit >> 4;
  const int g = unit & 15;

  const int cA = (8 * j) / 9;
  const int cB = (8 * j + 7) / 9; // == cA for j=0, j=8
  const int y0 = sl * RPS;
  const int y1 = (y0 + RPS < HM) ? y0 + RPS : HM; // pixel rows [y0,y1)
  const int nstage = ((y1 + 2 < HH) ? y1 + 2 : HH) - y0; // <= 34

  __shared__ __attribute__((aligned(16))) float lds[2 * STG_STRIDE];
  __shared__ float red[36 * 4];

  // ---- stage: global -> LDS, one aligned dwordx4 stream per channel ----
  const int nch = (cB != cA) ? 2 : 1;
  for (int ch = 0; ch < nch; ++ch) {
    const int c = ch ? cB : cA;
    const float4v* src = (const float4v*)(feat +
        (size_t)(b * CC + g * CG + c) * HWSZ + (size_t)y0 * WW);
    float4v* dst = (float4v*)(lds + ch * STG_STRIDE);
    const int nvec = nstage * (WW / 4); // rows * 48
    for (int i = (int)threadIdx.x; i < nvec; i += 256) dst[i] = src[i];
  }
  __syncthreads();

  // ---- per-d LDS base: buffer select + (ki,kj) shift ----
  int ldb[8];
#pragma unroll
  for (int d = 0; d < 8; ++d) {
    const int f = j * 8 + d;
    const int c = f / 9;
    const int k = f % 9;
    ldb[d] = (c == cA ? 0 : STG_STRIDE) + (k / 3) * WW + (k % 3);
  }

  float acc[36];
#pragma unroll
  for (int i = 0; i < 36; ++i) acc[i] = 0.0f;

  const int npix = (y1 - y0) * WM;
  for (int l = (int)threadIdx.x; l < npix; l += 256) {
    const int y = l / WM;
    const int x = l - y * WM;
    const int o = y * WW + x;
    float v[8];
#pragma unroll
    for (int d = 0; d < 8; ++d) v[d] = lds[ldb[d] + o];
#pragma unroll
    for (int d = 0; d < 8; ++d) acc[d] += v[d] * v[d];
    int p = 8;
#pragma unroll
    for (int c = 0; c < 8; ++c)
#pragma unroll
      for (int d = c + 1; d < 8; ++d) acc[p++] += v[c] * v[d];
  }

  // ---- block reduction: wave butterfly then LDS across 4 waves ----
  const int lane = threadIdx.x & 63;
  const int wave = threadIdx.x >> 6;
#pragma unroll
  for (int i = 0; i < 36; ++i) {
    float v = acc[i];
    for (int o = 32; o > 0; o >>= 1) v += __shfl_down(v, o, 64);
    if (lane == 0) red[i * 4 + wave] = v;
  }
  __syncthreads();
  if (threadIdx.x < 36) {
    const int i = threadIdx.x;
    const int tri = unit * 9 + j;
    g_part[(tri * SPLIT + sl) * 36 + i] =
        red[i * 4] + red[i * 4 + 1] + red[i * 4 + 2] + red[i * 4 + 3];
  }
}

// -------- Phase 1b: reduce slices, 8x8 argmin, emit phase2 tables ---------
__global__ __launch_bounds__(64) void phase1b_kernel() {
  const int tri = blockIdx.x * 64 + (int)threadIdx.x;
  if (tri >= NTRIPLE) return;
  const int b = tri / (GG * 9);
  const int rem = tri % (GG * 9);
  const int g = rem / 9;
  const int j = rem % 9;

  float tot[36];
#pragma unroll
  for (int i = 0; i < 36; ++i) tot[i] = 0.0f;
  for (int s = 0; s < SPLIT; ++s)
#pragma unroll
    for (int i = 0; i < 36; ++i) tot[i] += g_part[(tri * SPLIT + s) * 36 + i];

  float sq[8], gm[8][8];
#pragma unroll
  for (int i = 0; i < 8; ++i) sq[i] = tot[i];
  {
    int p = 8;
    for (int c = 0; c < 8; ++c)
      for (int d = c + 1; d < 8; ++d) {
        gm[c][d] = tot[p];
        gm[d][c] = tot[p];
        ++p;
      }
  }
  // per-row argmin with inf diagonal, first-occurrence tie-break
  int nn[8];
  for (int c = 0; c < 8; ++c) {
    float best = INFINITY;
    int bi = 0;
    for (int d = 0; d < 8; ++d) {
      if (d == c) continue;
      const float d2 = sq[c] + sq[d] - 2.0f * gm[c][d];
      if (d2 < best) {
        best = d2;
        bi = d;
      }
    }
    nn[c] = bi;
  }
  int um = 0;
  for (int c = 0; c < 8; ++c) um = um > nn[c] ? um : nn[c];
  int cnt = 0;
  for (int c = 0; c < 8; ++c) cnt += (nn[c] == um) ? 1 : 0;

  // scale = c_max/8 (exact: int * power of two); rel = neighbor offset
  // relative to the query pixel, constant over (h,w).
  const float sc = (float)cnt * 0.125f;
  const int fn = j * 8 + um;
  const int cn = fn / 9;
  const int kn = fn % 9;
  const int kin = kn / 3, kjn = kn % 3;
  for (int d = 0; d < 8; ++d) {
    const int f = j * 8 + d;
    const int cl = f / 9;
    const int k = f % 9;
    const int ki = k / 3, kj = k % 3;
    const int rel = (cn - cl) * HWSZ + (kin - ki) * WW + (kjn - kj);
    const int tix = (b * GG + g) * 72 + f;
    g_rel[tix] = rel;
    g_scl[tix] = sc;
  }
}

// -------- Phase 2 main: interior float4 groups, no masks ------------------
// XCD-locality swizzle: all 144 blocks (8 planes x 18) of one (b,g) unit on
// one XCD. 2 float4 groups per thread amortize the table prologue.
// Edge pixels are skipped here and written by phase2_edge (disjoint sets).
__global__ __launch_bounds__(256) void phase2_main_kernel(
    const float* __restrict__ feat, float* __restrict__ out) {
  const int B = blockIdx.x;      // 0..4607
  const int xcd = B & 7;
  const int slot = B >> 3;       // 0..575
  const int unit = xcd * 4 + slot / 144; // (b,g) composite, 0..31
  const int r = slot % 144;
  const int cl = r / 18;         // local channel 0..7
  const int blk = r % 18;        // 18 x 2048 px = one plane
  const int plane = unit * 8 + cl; // == b*CC + ch

  const int tbase = unit * 72 + cl * 9;
  int rel[9];
  float scl[9];
#pragma unroll
  for (int k = 0; k < 9; ++k) {
    rel[k] = g_rel[tbase + k];
    scl[k] = g_scl[tbase + k];
  }

  const float* pb = feat + (size_t)plane * HWSZ;
  float* ob = out + (size_t)plane * HWSZ;
  const bool b1 = (unit >= GG); // b != 0
  const int i0 = blk * 2048 + (int)threadIdx.x * 4;

#pragma unroll
  for (int gidx = 0; gidx < 2; ++gidx) {
    const int inner = i0 + gidx * 1024;
    const int h = inner / WW;
    const int w0 = inner % WW;
    if (h >= 2 && h < HM && w0 >= 4 && w0 < 188) {
      const float* p = pb + inner;
      const float4v v = *(const float4v*)p;
      float4v acc = {0.0f, 0.0f, 0.0f, 0.0f};
#pragma unroll
      for (int k = 0; k < 9; ++k) {
        const float4a n = *(const float4a*)(p + rel[k]);
        const float s = scl[k];
        // exact reference op order: round(v*n*cm)/8 == round(v*n*(cm/8))
        acc.x += floorf(v.x * n.x * s);
        acc.y += floorf(v.y * n.y * s);
        acc.z += floorf(v.z * n.z * s);
        acc.w += floorf(v.w * n.w * s);
      }
      if (b1) { // interior => n_valid = 9
        acc.x += 9.0f * v.x;
        acc.y += 9.0f * v.y;
        acc.z += 9.0f * v.z;
        acc.w += 9.0f * v.w;
      }
      *(float4v*)(ob + inner) = acc;
    }
  }
}

// -------- Phase 2 edge: border pixels, clamped scalar path ----------------
// 2272 px per plane: rows {0,1,190,191} (768) + cols {0..3,188..191} for
// h in [2,190) (1504). 256 planes * 2272 = 581632 = 2272 blocks * 256.
__global__ __launch_bounds__(256) void phase2_edge_kernel(
    const float* __restrict__ feat, float* __restrict__ out) {
  const int gid = blockIdx.x * 256 + (int)threadIdx.x;
  const int plane = gid / 2272;
  const int ei = gid % 2272;
  int h, w;
  if (ei < 768) {
    const int r = ei / WW; // 0..3
    h = (r < 2) ? r : r + 188; // 0,1,190,191
    w = ei % WW;
  } else {
    const int e2 = ei - 768;
    h = 2 + (e2 >> 3);
    const int w8 = e2 & 7;
    w = (w8 < 4) ? w8 : w8 + 184; // 0..3, 188..191
  }
  const int g = (plane % CC) >> 3;
  const int cl = (plane % CC) & 7;
  const int tbase = ((plane / CC) * GG + g) * 72 + cl * 9;

  int rel[9];
  float scl[9];
#pragma unroll
  for (int k = 0; k < 9; ++k) {
    rel[k] = g_rel[tbase + k];
    scl[k] = g_scl[tbase + k];
  }

  const int idx = plane * HWSZ + h * WW + w;
  const float* p = feat + idx;
  const float v = *p;
  float acc = 0.0f;
  int nv = 0;
#pragma unroll
  for (int k = 0; k < 9; ++k) {
    const int ki = k / 3, kj = k % 3; // compile-time
    const int y = h - ki, x = w - kj;
    const bool valid = ((unsigned)y < (unsigned)HM) & ((unsigned)x < (unsigned)WM);
    const int o = valid ? rel[k] : 0; // clamp keeps the load in-bounds
    const float n = p[o];
    const float fl = floorf(v * n * scl[k]);
    acc += valid ? fl : 0.0f;
    nv += valid ? 1 : 0;
  }
  if (plane >= CC) acc += (float)nv * v;
  out[idx] = acc;
}

extern "C" void kernel_launch(void* const* d_in, const int* in_sizes, int n_in,
                              void* d_out, int out_size, void* d_ws,
                              size_t ws_size, hipStream_t stream) {
  const float* feat = (const float*)d_in[0];
  float* out = (float*)d_out;
  (void)d_ws;
  (void)ws_size;

  phase1a_kernel<<<NTRIPLE * SPLIT, 256, 0, stream>>>(feat);
  phase1b_kernel<<<(NTRIPLE + 63) / 64, 64, 0, stream>>>();

  phase2_main_kernel<<<BB * CC * 18, 256, 0, stream>>>(feat, out);
  phase2_edge_kernel<<<2272, 256, 0, stream>>>(feat, out);
}

// Round 8
// 136.229 us; speedup vs baseline: 1.1252x; 1.1252x over previous
//
#include <hip/hip_runtime.h>
#include <hip/hip_bf16.h>
#include <math.h>

// Problem constants (B=2, C=128, G=16, Cg=8, K=3, H=W=192)
#define BB 2
#define CC 128
#define GG 16
#define CG 8
#define HH 192
#define WW 192
#define HM 190
#define WM 190
#define LL (HM * WM)          // 36100
#define HWSZ (HH * WW)        // 36864
#define NTRIPLE (BB * GG * 9) // 288
#define SPLIT 6               // row slices for phase1 parallelism
#define ROWS_PER_SLICE 32     // 6*32 >= 190

// 4-byte-aligned float4 for unaligned (dword-aligned) vector loads.
typedef float float4a __attribute__((ext_vector_type(4), aligned(4)));
typedef float float4v __attribute__((ext_vector_type(4)));

// Module-owned scratch (d_ws size unverified; writing it corrupted the
// harness pristine input copy in R0). Everything below is fully rewritten
// on every call before being read (same stream) -> identical work per call.
__device__ float g_part[NTRIPLE * SPLIT * 36]; // per-slice partial sums
__device__ int g_rel[BB * GG * 72];            // phase2: neighbor rel offset
__device__ float g_scl[BB * GG * 72];          // phase2: c_max/8

// -------- Phase 1a: per (b,g,j,rowslice) partial Gram sums, float4 --------
// R7 evidence: compiler reported VGPR=52/68 against a ~100-reg live set
// (acc[36]+v[32]+bases) -> accumulators churned through AGPRs, inflating
// VALU ~3.7x over the FMA floor across R4-R6. Fix: __launch_bounds__(256,4)
// raises the VGPR cap to 128 (grid only supplies ~6.75 blocks/CU, so
// occupancy above 4 blocks/CU was free anyway). LDS staging (R7) regressed:
// bank conflicts + occupancy loss; reverted to global float4 loads.
__global__ __launch_bounds__(256, 4) void phase1a_kernel(
    const float* __restrict__ feat) {
  const int B = blockIdx.x;      // 0..1727
  const int xcd = B & 7;         // XCD-locality swizzle (kept: halved FETCH)
  const int slot = B >> 3;       // 0..215
  const int unit = xcd * 4 + slot / 54; // (b,g) composite, 0..31
  const int r = slot % 54;
  const int j = r / 6;
  const int sl = r % 6;
  const int b = unit >> 4;
  const int g = unit & 15;

  const float* base[8];
#pragma unroll
  for (int d = 0; d < 8; ++d) {
    const int f = j * 8 + d;
    const int c = f / 9;
    const int k = f % 9;
    const int ki = k / 3, kj = k % 3;
    base[d] = feat + (size_t)(b * CC + g * CG + c) * HWSZ + ki * WW + kj;
  }

  float acc[36];
#pragma unroll
  for (int i = 0; i < 36; ++i) acc[i] = 0.0f;

  const int y0 = sl * ROWS_PER_SLICE;
  const int y1 = (y0 + ROWS_PER_SLICE < HM) ? y0 + ROWS_PER_SLICE : HM;
  const int ng = (y1 - y0) * 48; // 48 groups of 4 px per row (190 cols)

  // Incremental (y,xg) update: stride 256 = 5 rows + 16 groups.
  int y = y0 + (int)threadIdx.x / 48;
  int xg = (int)threadIdx.x % 48;
  for (int gi = (int)threadIdx.x; gi < ng; gi += 256) {
    // Group 47 covers x=188,189 only; load shifted to x=186 so the dwordx4
    // stays in-bounds, then zero the two duplicate elements.
    const bool tail = (xg == 47);
    const int xL = tail ? 186 : xg * 4;
    const int ro = y * WW + xL;
    float4a v[8];
#pragma unroll
    for (int d = 0; d < 8; ++d) v[d] = *(const float4a*)(base[d] + ro);
    if (tail) {
#pragma unroll
      for (int d = 0; d < 8; ++d) {
        v[d].x = 0.0f;
        v[d].y = 0.0f;
      }
    }
#pragma unroll
    for (int d = 0; d < 8; ++d)
      acc[d] += v[d].x * v[d].x + v[d].y * v[d].y + v[d].z * v[d].z +
                v[d].w * v[d].w;
    int p = 8;
#pragma unroll
    for (int c = 0; c < 8; ++c)
#pragma unroll
      for (int d = c + 1; d < 8; ++d) {
        acc[p] += v[c].x * v[d].x + v[c].y * v[d].y + v[c].z * v[d].z +
                  v[c].w * v[d].w;
        ++p;
      }
    xg += 16;
    y += 5;
    if (xg >= 48) {
      xg -= 48;
      y += 1;
    }
  }

  // Wave shuffle reduce (64 lanes) then LDS across 4 waves.
  __shared__ float red[36 * 4];
  const int lane = threadIdx.x & 63;
  const int wave = threadIdx.x >> 6;
#pragma unroll
  for (int i = 0; i < 36; ++i) {
    float v = acc[i];
    for (int o = 32; o > 0; o >>= 1) v += __shfl_down(v, o, 64);
    if (lane == 0) red[i * 4 + wave] = v;
  }
  __syncthreads();
  if (threadIdx.x < 36) {
    const int i = threadIdx.x;
    const int tri = unit * 9 + j;
    g_part[(tri * SPLIT + sl) * 36 + i] =
        red[i * 4] + red[i * 4 + 1] + red[i * 4 + 2] + red[i * 4 + 3];
  }
}

// -------- Phase 1b: reduce slices, 8x8 argmin, emit phase2 tables ---------
__global__ __launch_bounds__(64) void phase1b_kernel() {
  const int tri = blockIdx.x * 64 + (int)threadIdx.x;
  if (tri >= NTRIPLE) return;
  const int b = tri / (GG * 9);
  const int rem = tri % (GG * 9);
  const int g = rem / 9;
  const int j = rem % 9;

  float tot[36];
#pragma unroll
  for (int i = 0; i < 36; ++i) tot[i] = 0.0f;
  for (int s = 0; s < SPLIT; ++s)
#pragma unroll
    for (int i = 0; i < 36; ++i) tot[i] += g_part[(tri * SPLIT + s) * 36 + i];

  float sq[8], gm[8][8];
#pragma unroll
  for (int i = 0; i < 8; ++i) sq[i] = tot[i];
  {
    int p = 8;
    for (int c = 0; c < 8; ++c)
      for (int d = c + 1; d < 8; ++d) {
        gm[c][d] = tot[p];
        gm[d][c] = tot[p];
        ++p;
      }
  }
  // per-row argmin with inf diagonal, first-occurrence tie-break
  int nn[8];
  for (int c = 0; c < 8; ++c) {
    float best = INFINITY;
    int bi = 0;
    for (int d = 0; d < 8; ++d) {
      if (d == c) continue;
      const float d2 = sq[c] + sq[d] - 2.0f * gm[c][d];
      if (d2 < best) {
        best = d2;
        bi = d;
      }
    }
    nn[c] = bi;
  }
  int um = 0;
  for (int c = 0; c < 8; ++c) um = um > nn[c] ? um : nn[c];
  int cnt = 0;
  for (int c = 0; c < 8; ++c) cnt += (nn[c] == um) ? 1 : 0;

  // scale = c_max/8 (exact: int * power of two); rel = neighbor offset
  // relative to the query pixel, constant over (h,w).
  const float sc = (float)cnt * 0.125f;
  const int fn = j * 8 + um;
  const int cn = fn / 9;
  const int kn = fn % 9;
  const int kin = kn / 3, kjn = kn % 3;
  for (int d = 0; d < 8; ++d) {
    const int f = j * 8 + d;
    const int cl = f / 9;
    const int k = f % 9;
    const int ki = k / 3, kj = k % 3;
    const int rel = (cn - cl) * HWSZ + (kin - ki) * WW + (kjn - kj);
    const int tix = (b * GG + g) * 72 + f;
    g_rel[tix] = rel;
    g_scl[tix] = sc;
  }
}

// -------- Phase 2 main: interior float4 groups, no masks ------------------
// XCD-locality swizzle: all 144 blocks (8 planes x 18) of one (b,g) unit on
// one XCD. 2 float4 groups per thread amortize the table prologue.
// Edge pixels are skipped here and written by phase2_edge (disjoint sets).
__global__ __launch_bounds__(256) void phase2_main_kernel(
    const float* __restrict__ feat, float* __restrict__ out) {
  const int B = blockIdx.x;      // 0..4607
  const int xcd = B & 7;
  const int slot = B >> 3;       // 0..575
  const int unit = xcd * 4 + slot / 144; // (b,g) composite, 0..31
  const int r = slot % 144;
  const int cl = r / 18;         // local channel 0..7
  const int blk = r % 18;        // 18 x 2048 px = one plane
  const int plane = unit * 8 + cl; // == b*CC + ch

  const int tbase = unit * 72 + cl * 9;
  int rel[9];
  float scl[9];
#pragma unroll
  for (int k = 0; k < 9; ++k) {
    rel[k] = g_rel[tbase + k];
    scl[k] = g_scl[tbase + k];
  }

  const float* pb = feat + (size_t)plane * HWSZ;
  float* ob = out + (size_t)plane * HWSZ;
  const bool b1 = (unit >= GG); // b != 0
  const int i0 = blk * 2048 + (int)threadIdx.x * 4;

#pragma unroll
  for (int gidx = 0; gidx < 2; ++gidx) {
    const int inner = i0 + gidx * 1024;
    const int h = inner / WW;
    const int w0 = inner % WW;
    if (h >= 2 && h < HM && w0 >= 4 && w0 < 188) {
      const float* p = pb + inner;
      const float4v v = *(const float4v*)p;
      float4v acc = {0.0f, 0.0f, 0.0f, 0.0f};
#pragma unroll
      for (int k = 0; k < 9; ++k) {
        const float4a n = *(const float4a*)(p + rel[k]);
        const float s = scl[k];
        // exact reference op order: round(v*n*cm)/8 == round(v*n*(cm/8))
        acc.x += floorf(v.x * n.x * s);
        acc.y += floorf(v.y * n.y * s);
        acc.z += floorf(v.z * n.z * s);
        acc.w += floorf(v.w * n.w * s);
      }
      if (b1) { // interior => n_valid = 9
        acc.x += 9.0f * v.x;
        acc.y += 9.0f * v.y;
        acc.z += 9.0f * v.z;
        acc.w += 9.0f * v.w;
      }
      *(float4v*)(ob + inner) = acc;
    }
  }
}

// -------- Phase 2 edge: border pixels, clamped scalar path ----------------
// 2272 px per plane: rows {0,1,190,191} (768) + cols {0..3,188..191} for
// h in [2,190) (1504). 256 planes * 2272 = 581632 = 2272 blocks * 256.
__global__ __launch_bounds__(256) void phase2_edge_kernel(
    const float* __restrict__ feat, float* __restrict__ out) {
  const int gid = blockIdx.x * 256 + (int)threadIdx.x;
  const int plane = gid / 2272;
  const int ei = gid % 2272;
  int h, w;
  if (ei < 768) {
    const int r = ei / WW; // 0..3
    h = (r < 2) ? r : r + 188; // 0,1,190,191
    w = ei % WW;
  } else {
    const int e2 = ei - 768;
    h = 2 + (e2 >> 3);
    const int w8 = e2 & 7;
    w = (w8 < 4) ? w8 : w8 + 184; // 0..3, 188..191
  }
  const int g = (plane % CC) >> 3;
  const int cl = (plane % CC) & 7;
  const int tbase = ((plane / CC) * GG + g) * 72 + cl * 9;

  int rel[9];
  float scl[9];
#pragma unroll
  for (int k = 0; k < 9; ++k) {
    rel[k] = g_rel[tbase + k];
    scl[k] = g_scl[tbase + k];
  }

  const int idx = plane * HWSZ + h * WW + w;
  const float* p = feat + idx;
  const float v = *p;
  float acc = 0.0f;
  int nv = 0;
#pragma unroll
  for (int k = 0; k < 9; ++k) {
    const int ki = k / 3, kj = k % 3; // compile-time
    const int y = h - ki, x = w - kj;
    const bool valid = ((unsigned)y < (unsigned)HM) & ((unsigned)x < (unsigned)WM);
    const int o = valid ? rel[k] : 0; // clamp keeps the load in-bounds
    const float n = p[o];
    const float fl = floorf(v * n * scl[k]);
    acc += valid ? fl : 0.0f;
    nv += valid ? 1 : 0;
  }
  if (plane >= CC) acc += (float)nv * v;
  out[idx] = acc;
}

extern "C" void kernel_launch(void* const* d_in, const int* in_sizes, int n_in,
                              void* d_out, int out_size, void* d_ws,
                              size_t ws_size, hipStream_t stream) {
  const float* feat = (const float*)d_in[0];
  float* out = (float*)d_out;
  (void)d_ws;
  (void)ws_size;

  phase1a_kernel<<<NTRIPLE * SPLIT, 256, 0, stream>>>(feat);
  phase1b_kernel<<<(NTRIPLE + 63) / 64, 64, 0, stream>>>();

  phase2_main_kernel<<<BB * CC * 18, 256, 0, stream>>>(feat, out);
  phase2_edge_kernel<<<2272, 256, 0, stream>>>(feat, out);
}